// Round 9
// baseline (128.059 us; speedup 1.0000x reference)
//
#include <hip/hip_runtime.h>
#include <hip/hip_bf16.h>
#include <cstdint>

#define NN    1024
#define FF    64
#define OUTF  128
#define KCAT  192
#define EPSV  1e-6f

typedef __attribute__((ext_vector_type(4))) float  f32x4;
typedef __attribute__((ext_vector_type(8))) __bf16 bf16x8;
typedef __attribute__((ext_vector_type(4))) __bf16 bf16x4;

#define MFMA16(a, b, c) __builtin_amdgcn_mfma_f32_16x16x32_bf16(a, b, c, 0, 0, 0)
#define GLOAD_LDS16(g, l)                                          \
    __builtin_amdgcn_global_load_lds(                              \
        (const __attribute__((address_space(1))) void*)(g),        \
        (__attribute__((address_space(3))) void*)(l), 16, 0, 0)

// ---------------------------------------------------------------------------
// Kernel 1: degree + diag-zero + f32->bf16 conversion of A, fused.
// BW-bound: 64MB read + 32MB write ~ 15us.
// ---------------------------------------------------------------------------
__global__ __launch_bounds__(256) void k_deg_cvt(const float* __restrict__ A,
                                                 float* __restrict__ d1,
                                                 float* __restrict__ sArr,
                                                 __bf16* __restrict__ Az) {
    int wave = threadIdx.x >> 6;
    int lane = threadIdx.x & 63;
    int row  = blockIdx.x * 4 + wave;          // [0, 16384)
    int i    = row & (NN - 1);                 // diag index within batch row
    const f32x4* rp = (const f32x4*)(A + (size_t)row * NN);
    __bf16* op = Az + (size_t)row * NN;
    float sum = 0.f;
#pragma unroll
    for (int t = 0; t < 4; ++t) {
        f32x4 v = rp[t * 64 + lane];
        int base = (t * 64 + lane) * 4;
#pragma unroll
        for (int q = 0; q < 4; ++q)
            if (base + q == i) v[q] = 0.f;     // zero diagonal
        sum += v[0] + v[1] + v[2] + v[3];
        bf16x4 o;
#pragma unroll
        for (int q = 0; q < 4; ++q) o[q] = (__bf16)v[q];
        *(bf16x4*)(op + base) = o;
    }
#pragma unroll
    for (int off = 32; off; off >>= 1) sum += __shfl_xor(sum, off);
    if (lane == 0) {
        float deg = 1.0f + sum;
        d1[row]   = 1.0f / (EPSV + deg);
        sArr[row] = 1.0f / (EPSV + sqrtf(deg));
    }
}

// ---------------------------------------------------------------------------
// Kernel 2: K-major bf16 copy of x + transposed bf16 kernel.
// (sxT is GONE — s is applied in-register inside k_main.)
// ---------------------------------------------------------------------------
__global__ __launch_bounds__(256) void k_prep(const float* __restrict__ x,
                                              const float* __restrict__ kern,
                                              __bf16* __restrict__ xT,
                                              __bf16* __restrict__ KT) {
    __shared__ float tile[64][65];
    int bid = blockIdx.x;                  // 0..255
    int b   = bid >> 4;
    int k0  = (bid & 15) * 64;
    const float* xp = x + ((size_t)b * NN + k0) * FF;
    for (int i = threadIdx.x; i < 64 * 64; i += 256) {
        int r = i >> 6, c = i & 63;
        tile[r][c] = xp[r * FF + c];
    }
    __syncthreads();
    for (int i = threadIdx.x; i < 64 * 64; i += 256) {
        int c = i >> 6, kk = i & 63;
        size_t o = ((size_t)b * FF + c) * NN + k0 + kk;
        xT[o] = (__bf16)tile[kk][c];
    }
    if (threadIdx.x < 96) {
        int idx = bid * 96 + threadIdx.x;
        int c = idx / KCAT;
        int k = idx - c * KCAT;
        KT[idx] = (__bf16)kern[k * OUTF + c];
    }
}

// ---------------------------------------------------------------------------
// Kernel 3: main fused kernel.
//   - counted-vmcnt DMA pipeline, 3 buffers, DEPTH-2 prefetch: STAGE(t+2)
//     issues BEFORE compute(t) (buffer roles t%3 / (t+1)%3 / (t+2)%3 are
//     disjoint), so 2 tiles stream while 1 computes.
//   - ONE barrier per phase (top). Safe: passing barrier t proves all waves'
//     tile-(t-1) ds_reads retired -> buf[(t+2)%3 == (t-1)%3] reusable.
//   - sx NOT staged: s vector (4KB/batch) staged once; Q's B-fragment is
//     synthesized per k-step:  sf = bf16(s_k * float(xf)).
//   - row-major LDS + XOR 16B-slot swizzle both sides (R8, verified).
// Grid 512 = 16 batches x 32 row-tiles (BM=32). 512 threads = 8 waves
// (rg = w>>2 row group, fg = w&3 feature group). LDS 76KB -> 2 blocks/CU.
// Per tile per wave: 3 DMA (A, x lo, x hi) -> vmcnt(3) steady / (0) last.
// Waves 0-3 carry one extra (oldest) s-load: retires first, counts stay valid.
// Epilogue: o1/o2/o3 -> bf16 os (overlay buf0) -> swapped-operand GEMM vs KT
// -> bias+relu -> coalesced f32x4 stores.
// ---------------------------------------------------------------------------
__global__ __launch_bounds__(512, 4) void k_main(const __bf16* __restrict__ Az,
                                                 const float* __restrict__ x,
                                                 const float* __restrict__ bias,
                                                 const float* __restrict__ d1g,
                                                 const float* __restrict__ sg,
                                                 const __bf16* __restrict__ xT,
                                                 const __bf16* __restrict__ KT,
                                                 float* __restrict__ out) {
    __shared__ __align__(16) char smem[77824];   // 3x24KB bufs | 4KB s | os->buf0

    const int tid  = threadIdx.x;
    const int w    = tid >> 6;          // wave 0..7
    const int lane = tid & 63;
    const int l15  = lane & 15;
    const int hi   = lane >> 4;         // 0..3
    const int h8   = hi * 8;

    // XCD-chunked swizzle: XCD xcd gets idx [xcd*64, xcd*64+64) = 2 batches.
    const int idx  = (blockIdx.x & 7) * 64 + (blockIdx.x >> 3);
    const int b    = idx >> 5;
    const int row0 = (idx & 31) * 32;

    // ---- staging sources: 4 consecutive rows/chunk, XOR slot within row ----
    const int rA = 4 * w + hi;                     // A tile row for this lane
    const int sA = (l15 ^ (rA & 7)) * 8;
    const __bf16* Asrc = Az + (size_t)(b * NN + row0 + rA) * NN + sA;

    const int f0 = 4 * w + hi;                     // x row, chunk w
    const int s0 = (l15 ^ (f0 & 7)) * 8;
    const int f1 = 32 + 4 * w + hi;                // x row, chunk w+8
    const int s1 = (l15 ^ (f1 & 7)) * 8;
    const __bf16* Xsrc0 = xT + (size_t)(b * FF + f0) * NN + s0;
    const __bf16* Xsrc1 = xT + (size_t)(b * FF + f1) * NN + s1;

#define STAGE(t, pb)                                                     \
    {                                                                    \
        char* bb = smem + (pb) * 24576;                                  \
        const int ko = (t) * 128;                                        \
        GLOAD_LDS16(Asrc + ko,  bb + w * 1024);                          \
        GLOAD_LDS16(Xsrc0 + ko, bb + 8192 + w * 1024);                   \
        GLOAD_LDS16(Xsrc1 + ko, bb + 8192 + (w + 8) * 1024);             \
    }

    // ---- prologue: s vector (oldest, waves 0-3), then tiles 0,1 ----
    if (w < 4) {
        GLOAD_LDS16(sg + (size_t)b * NN + w * 256 + lane * 4,
                    smem + 73728 + w * 1024);
    }
    STAGE(0, 0)
    STAGE(1, 1)

    const int rg = w >> 2;     // compute row group
    const int fg = w & 3;      // compute feature group

    const int swz   = (l15 & 7) << 4;
    const int aBase = (rg * 16 + l15) * 256;
    const int xBase = 8192 + (fg * 16 + l15) * 256;
    const char* sVec = smem + 73728;

    f32x4 P = {}, Q = {};
#pragma unroll
    for (int t = 0; t < 8; ++t) {
        if (t < 7) { asm volatile("s_waitcnt vmcnt(3)" ::: "memory"); }
        else       { asm volatile("s_waitcnt vmcnt(0)" ::: "memory"); }
        __builtin_amdgcn_s_barrier();            // tile t resident, buffers free
        __builtin_amdgcn_sched_barrier(0);
        if (t < 6) STAGE(t + 2, (t + 2) % 3)     // depth-2: issue BEFORE compute
        __builtin_amdgcn_sched_barrier(0);
        {
            const char* bb = smem + (t % 3) * 24576;
            const char* sT = sVec + t * 512;     // this tile's 128 s values
#pragma unroll
            for (int ks = 0; ks < 4; ++ks) {
                const int ko = (ks * 64 + hi * 16) ^ swz;
                bf16x8 a  = *(const bf16x8*)(bb + aBase + ko);
                bf16x8 xf = *(const bf16x8*)(bb + xBase + ko);
                f32x4 sl = *(const f32x4*)(sT + ks * 128 + hi * 32);
                f32x4 sh = *(const f32x4*)(sT + ks * 128 + hi * 32 + 16);
                bf16x8 sf;
#pragma unroll
                for (int m = 0; m < 4; ++m) {
                    sf[m]     = (__bf16)(sl[m] * (float)xf[m]);
                    sf[m + 4] = (__bf16)(sh[m] * (float)xf[m + 4]);
                }
                P = MFMA16(a, xf, P);
                Q = MFMA16(a, sf, Q);
            }
        }
        __builtin_amdgcn_sched_barrier(0);       // keep iterations ordered
    }
#undef STAGE

    // ---- build o = [o1 | o2 | o3] in LDS (overlay buf0) -------------------
    __bf16 (*os)[216] = (__bf16(*)[216])smem;    // 32 x 216 x 2B = 13.5KB
#pragma unroll
    for (int j = 0; j < 4; ++j) {
        int rr   = rg * 16 + hi * 4 + j;
        int grow = b * NN + row0 + rr;
        float dv = d1g[grow];
        float sv = sg[grow];
        int cc   = fg * 16 + l15;
        float xv = x[(size_t)grow * FF + cc];
        os[rr][cc]       = (__bf16)P[j];
        os[rr][64 + cc]  = (__bf16)(dv * (P[j] + xv));
        os[rr][128 + cc] = (__bf16)(sv * (Q[j] + sv * xv));
    }
    __syncthreads();

    // ---- epilogue GEMM (swapped operands): out[32x128] --------------------
    const int rge = w >> 2;         // row half
    const int cge = w & 3;          // col group of 32
    f32x4 e0 = {}, e1 = {};
#pragma unroll
    for (int ks = 0; ks < 6; ++ks) {
        bf16x8 of = *(const bf16x8*)&os[rge * 16 + l15][ks * 32 + h8];
        bf16x8 k0 = *(const bf16x8*)&KT[(size_t)(cge * 32 + l15) * KCAT + ks * 32 + h8];
        bf16x8 k1 = *(const bf16x8*)&KT[(size_t)(cge * 32 + 16 + l15) * KCAT + ks * 32 + h8];
        e0 = MFMA16(k0, of, e0);    // D rows = out cols, D cols = os rows
        e1 = MFMA16(k1, of, e1);
    }
    {
        const size_t orow = (size_t)(b * NN + row0 + rge * 16 + l15) * OUTF;
#pragma unroll
        for (int g = 0; g < 2; ++g) {
            f32x4 ev = g ? e1 : e0;
            int col0 = cge * 32 + g * 16 + hi * 4;
            f32x4 bv = *(const f32x4*)&bias[col0];
            f32x4 rv;
#pragma unroll
            for (int j = 0; j < 4; ++j) {
                float v = ev[j] + bv[j];
                rv[j] = v > 0.f ? v : 0.f;
            }
            *(f32x4*)&out[orow + col0] = rv;
        }
    }
}

// ---------------------------------------------------------------------------
extern "C" void kernel_launch(void* const* d_in, const int* in_sizes, int n_in,
                              void* d_out, int out_size, void* d_ws, size_t ws_size,
                              hipStream_t stream) {
    const float* x    = (const float*)d_in[0];
    const float* A    = (const float*)d_in[1];
    const float* kern = (const float*)d_in[2];
    const float* bias = (const float*)d_in[3];
    float* out = (float*)d_out;

    char* ws = (char*)d_ws;
    __bf16* Az  = (__bf16*)(ws);                                   // 32 MB
    float*  d1  = (float*)(ws + 33554432);                         // 64 KB
    float*  s   = (float*)(ws + 33554432 + 65536);                 // 64 KB
    __bf16* xT  = (__bf16*)(ws + 33554432 + 131072);               // 2 MB
    __bf16* KT  = (__bf16*)(ws + 33554432 + 131072 + 2097152);     // 48 KB
    (void)ws_size; (void)in_sizes; (void)n_in; (void)out_size;

    k_deg_cvt<<<dim3(4096), dim3(256), 0, stream>>>(A, d1, s, Az);
    k_prep<<<dim3(256), dim3(256), 0, stream>>>(x, kern, xT, KT);
    k_main<<<dim3(512), dim3(512), 0, stream>>>(Az, x, bias, d1, s, xT, KT, out);
}